// Round 1
// baseline (215.764 us; speedup 1.0000x reference)
//
#include <hip/hip_runtime.h>
#include <math.h>

#define NS 32          // NSAMPLE
#define WPB 4          // waves per block

__global__ __launch_bounds__(256) void qgd_kernel(
    const float* __restrict__ xyz,        // (B*N_per, 3)
    const float* __restrict__ new_xyz,    // (B*M_per, 3)
    const float* __restrict__ new_xyz_r,  // (B*M_per, 1)
    const float* __restrict__ features,   // (B*N_per, C)
    const float* __restrict__ tdec,       // (1,)
    float* __restrict__ out,
    int N_per, int M_per, int C, int M_tot)
{
    // numpy reference does NOT fuse mul+add; a contracted fma can flip the
    // borderline d2 < r^2 compare and change selected indices (idx is graded
    // at 2% absolute -> one flip fails). Keep plain IEEE f32 ops.
#pragma clang fp contract(off)

    __shared__ int sIdx[WPB][NS];

    const int lane = threadIdx.x & 63;
    const int wv   = threadIdx.x >> 6;
    const int m    = blockIdx.x * WPB + wv;
    const bool active = (m < M_tot);

    int   cnt = 0;
    float qx = 0.f, qy = 0.f, qz = 0.f, r_orig = 0.f, real_t = 0.1f;
    const float* xb = xyz;
    int b = 0;

    if (active) {
        b  = m / M_per;
        qx = new_xyz[(size_t)m * 3 + 0];
        qy = new_xyz[(size_t)m * 3 + 1];
        qz = new_xyz[(size_t)m * 3 + 2];
        r_orig = new_xyz_r[m];
        real_t = 0.1f * tdec[0];                 // TEMPERATURE * decay
        float er  = r_orig + real_t * 5.0f;      // explore radius
        float er2 = er * er;
        xb = xyz + (size_t)b * N_per * 3;

        // ---- ball query: first NS in-ball indices in ascending order ----
        for (int base = 0; base < N_per; base += 64) {
            int p = base + lane;                 // N_per % 64 == 0
            float dx = xb[(size_t)p * 3 + 0] - qx;
            float dy = xb[(size_t)p * 3 + 1] - qy;
            float dz = xb[(size_t)p * 3 + 2] - qz;
            float d2 = dx * dx;
            d2 = d2 + dy * dy;                   // numpy left-fold order
            d2 = d2 + dz * dz;
            bool hit = d2 < er2;                 // strict <
            unsigned long long msk = __ballot(hit);
            if (hit) {
                int slot = cnt + (int)__popcll(msk & ((1ull << lane) - 1ull));
                if (slot < NS) sIdx[wv][slot] = p;
            }
            cnt += (int)__popcll(msk);           // wave-uniform
            if (cnt >= NS) break;                // wave-uniform early exit
        }
    }
    __syncthreads();

    const bool empty = (cnt == 0);
    // pad slots >= cnt with first hit (or 0 if empty) — matches reference
    if (active && lane < NS && lane >= cnt) {
        sIdx[wv][lane] = empty ? 0 : sIdx[wv][0];
    }
    __syncthreads();

    if (!active) return;

    const int    j       = lane & 31;            // sample slot
    const int    pj      = sIdx[wv][j];
    const size_t nf_base = (size_t)m * (3 + C) * NS;
    float* wout = out + (size_t)M_tot * (3 + C) * NS;   // weights block
    float* iout = wout + (size_t)M_tot * NS;            // idx block

    if (lane < NS) {
        float gx = 0.f, gy = 0.f, gz = 0.f;
        if (!empty) {
            gx = xb[(size_t)pj * 3 + 0] - qx;
            gy = xb[(size_t)pj * 3 + 1] - qy;
            gz = xb[(size_t)pj * 3 + 2] - qz;
        }
        float d2 = gx * gx;
        d2 = d2 + gy * gy;
        d2 = d2 + gz * gz;
        float dist = sqrtf(d2);
        // 1 - sigmoid(z) == 1/(1+exp(z)), z = (dist - r)/real_t
        float wt = 1.0f / (1.0f + expf((dist - r_orig) / real_t));
        out[nf_base + 0 * NS + j] = gx;
        out[nf_base + 1 * NS + j] = gy;
        out[nf_base + 2 * NS + j] = gz;
        wout[(size_t)m * NS + j] = wt;
        iout[(size_t)m * NS + j] = (float)pj;    // out buffer is f32; idx exact
    }

    // ---- grouped features: channel c, sample j -> out[m][3+c][j] ----
    // half-wave h covers channels h, h+2, h+4, ... ; a full-wave store of
    // channels (c, c+1) is one contiguous, 128B-aligned 256B segment.
    const float* frow = features + ((size_t)b * N_per + pj) * C;
    const int h = lane >> 5;
    for (int c = h; c < C; c += 2) {
        float v = empty ? 0.0f : frow[c];
        out[nf_base + (size_t)(3 + c) * NS + j] = v;
    }
}

extern "C" void kernel_launch(void* const* d_in, const int* in_sizes, int n_in,
                              void* d_out, int out_size, void* d_ws, size_t ws_size,
                              hipStream_t stream) {
    const float* xyz       = (const float*)d_in[0];
    // d_in[1] = xyz_batch_cnt (int32) — reference only uses its length (B)
    const float* new_xyz   = (const float*)d_in[2];
    const float* new_xyz_r = (const float*)d_in[3];
    // d_in[4] = new_xyz_batch_cnt — unused (even split, like the reference)
    const float* features  = (const float*)d_in[5];
    const float* tdec      = (const float*)d_in[6];

    const int B     = in_sizes[1];
    const int N_tot = in_sizes[0] / 3;
    const int M_tot = in_sizes[2] / 3;
    const int C     = in_sizes[5] / N_tot;
    const int N_per = N_tot / B;
    const int M_per = M_tot / B;

    const int blocks = (M_tot + WPB - 1) / WPB;
    qgd_kernel<<<blocks, 256, 0, stream>>>(xyz, new_xyz, new_xyz_r, features,
                                           tdec, (float*)d_out,
                                           N_per, M_per, C, M_tot);
}

// Round 2
// 139.057 us; speedup vs baseline: 1.5516x; 1.5516x over previous
//
#include <hip/hip_runtime.h>
#include <math.h>

#define NS 32          // NSAMPLE
#define WPB 4          // waves per block

__global__ __launch_bounds__(256) void qgd_kernel(
    const float* __restrict__ xyz,        // (B*N_per, 3)
    const float* __restrict__ new_xyz,    // (B*M_per, 3)
    const float* __restrict__ new_xyz_r,  // (B*M_per, 1)
    const float* __restrict__ features,   // (B*N_per, C)
    const float* __restrict__ tdec,       // (1,)
    float* __restrict__ out,
    int N_per, int M_per, int C, int M_tot)
{
    // numpy reference does NOT fuse mul+add; a contracted fma can flip the
    // borderline d2 < r^2 compare and change selected indices (idx is graded
    // at 2% absolute -> one flip fails). Keep plain IEEE f32 ops.
#pragma clang fp contract(off)

    __shared__ int sIdx[WPB][NS];

    const int lane = threadIdx.x & 63;
    const int wv   = threadIdx.x >> 6;
    const int m    = blockIdx.x * WPB + wv;
    const bool active = (m < M_tot);

    int   cnt = 0;
    float qx = 0.f, qy = 0.f, qz = 0.f, r_orig = 0.f, real_t = 0.1f;
    const float* xb = xyz;
    int b = 0;

    if (active) {
        b  = m / M_per;
        qx = new_xyz[(size_t)m * 3 + 0];
        qy = new_xyz[(size_t)m * 3 + 1];
        qz = new_xyz[(size_t)m * 3 + 2];
        r_orig = new_xyz_r[m];
        real_t = 0.1f * tdec[0];                 // TEMPERATURE * decay
        float er  = r_orig + real_t * 5.0f;      // explore radius
        float er2 = er * er;
        xb = xyz + (size_t)b * N_per * 3;

        const unsigned long long lt = (1ull << lane) - 1ull;

        // ---- ball query: first NS in-ball indices in ascending order ----
        // 256 points per iteration (4 strided 64-subblocks): hoist all 12
        // coalesced loads, then 4 ballots, ONE uniform break per 256 points.
        // This cuts the serialized load->ballot->break chain 4x for the
        // tail waves (queries with <32 in-ball points scan all of N_per).
        int base = 0;
        for (; base + 256 <= N_per; base += 256) {
            float d2k[4];
            #pragma unroll
            for (int k = 0; k < 4; ++k) {
                const float* pp = xb + (size_t)(base + k * 64 + lane) * 3;
                float dx = pp[0] - qx;
                float dy = pp[1] - qy;
                float dz = pp[2] - qz;
                float d2 = dx * dx;
                d2 = d2 + dy * dy;               // numpy left-fold order
                d2 = d2 + dz * dz;
                d2k[k] = d2;
            }
            #pragma unroll
            for (int k = 0; k < 4; ++k) {
                bool hit = d2k[k] < er2;         // strict <
                unsigned long long msk = __ballot(hit);
                if (hit) {
                    int slot = cnt + (int)__popcll(msk & lt);
                    if (slot < NS) sIdx[wv][slot] = base + k * 64 + lane;
                }
                cnt += (int)__popcll(msk);       // wave-uniform
            }
            if (cnt >= NS) break;                // wave-uniform early exit
        }
        // remainder (N_per not multiple of 256) — 64 at a time
        if (cnt < NS) {
            for (; base < N_per; base += 64) {
                int p = base + lane;
                bool inb = p < N_per;
                int pc = inb ? p : (N_per - 1);
                const float* pp = xb + (size_t)pc * 3;
                float dx = pp[0] - qx;
                float dy = pp[1] - qy;
                float dz = pp[2] - qz;
                float d2 = dx * dx;
                d2 = d2 + dy * dy;
                d2 = d2 + dz * dz;
                bool hit = inb && (d2 < er2);
                unsigned long long msk = __ballot(hit);
                if (hit) {
                    int slot = cnt + (int)__popcll(msk & lt);
                    if (slot < NS) sIdx[wv][slot] = p;
                }
                cnt += (int)__popcll(msk);
                if (cnt >= NS) break;
            }
        }
    }
    __syncthreads();

    const bool empty = (cnt == 0);
    // pad slots >= cnt with first hit (or 0 if empty) — matches reference
    if (active && lane < NS && lane >= cnt) {
        sIdx[wv][lane] = empty ? 0 : sIdx[wv][0];
    }
    __syncthreads();

    if (!active) return;

    const int    j       = lane & 31;            // sample slot
    const int    h       = lane >> 5;            // half-wave
    const int    pj      = sIdx[wv][j];
    const size_t nf_base = (size_t)m * (3 + C) * NS;
    float* wout = out + (size_t)M_tot * (3 + C) * NS;   // weights block
    float* iout = wout + (size_t)M_tot * NS;            // idx block

    if (lane < NS) {
        float gx = 0.f, gy = 0.f, gz = 0.f;
        if (!empty) {
            gx = xb[(size_t)pj * 3 + 0] - qx;
            gy = xb[(size_t)pj * 3 + 1] - qy;
            gz = xb[(size_t)pj * 3 + 2] - qz;
        }
        float d2 = gx * gx;
        d2 = d2 + gy * gy;
        d2 = d2 + gz * gz;
        float dist = sqrtf(d2);
        // 1 - sigmoid(z) == 1/(1+exp(z)), z = (dist - r)/real_t
        float wt = 1.0f / (1.0f + expf((dist - r_orig) / real_t));
        out[nf_base + 0 * NS + j] = gx;
        out[nf_base + 1 * NS + j] = gy;
        out[nf_base + 2 * NS + j] = gz;
        wout[(size_t)m * NS + j] = wt;
        iout[(size_t)m * NS + j] = (float)pj;    // out buffer is f32; idx exact
    }

    // ---- grouped features ----
    // lane (j,h) loads float4 = 4 channels of row pj per iteration:
    // 8 dwordx4 gather instrs/wave (~32-48 cache lines each) instead of
    // 32 scattered-dword instrs (64 lines each). Stores: dword per lane,
    // each instr covers 2 channels = 2 x 128B contiguous segments.
    const float* frow = features + ((size_t)b * N_per + pj) * C;
    for (int t = 0; t < C; t += 8) {
        float4 v = make_float4(0.f, 0.f, 0.f, 0.f);
        if (!empty) v = *(const float4*)(frow + t + h * 4);
        const size_t cb = nf_base + (size_t)(3 + t + h * 4) * NS + j;
        out[cb + 0 * NS] = v.x;
        out[cb + 1 * NS] = v.y;
        out[cb + 2 * NS] = v.z;
        out[cb + 3 * NS] = v.w;
    }
}

extern "C" void kernel_launch(void* const* d_in, const int* in_sizes, int n_in,
                              void* d_out, int out_size, void* d_ws, size_t ws_size,
                              hipStream_t stream) {
    const float* xyz       = (const float*)d_in[0];
    // d_in[1] = xyz_batch_cnt (int32) — reference only uses its length (B)
    const float* new_xyz   = (const float*)d_in[2];
    const float* new_xyz_r = (const float*)d_in[3];
    // d_in[4] = new_xyz_batch_cnt — unused (even split, like the reference)
    const float* features  = (const float*)d_in[5];
    const float* tdec      = (const float*)d_in[6];

    const int B     = in_sizes[1];
    const int N_tot = in_sizes[0] / 3;
    const int M_tot = in_sizes[2] / 3;
    const int C     = in_sizes[5] / N_tot;
    const int N_per = N_tot / B;
    const int M_per = M_tot / B;

    const int blocks = (M_tot + WPB - 1) / WPB;
    qgd_kernel<<<blocks, 256, 0, stream>>>(xyz, new_xyz, new_xyz_r, features,
                                           tdec, (float*)d_out,
                                           N_per, M_per, C, M_tot);
}

// Round 3
// 131.937 us; speedup vs baseline: 1.6354x; 1.0540x over previous
//
#include <hip/hip_runtime.h>
#include <math.h>

#define NS 32          // NSAMPLE
#define WPB 4          // waves per block
#define CHUNK 1024     // points per cooperative scan chunk (12 KB LDS)
#define TSTRIDE 36     // transpose tile j-stride in dwords (16B-aligned, bank-rotating)

// LDS budget: sBuf = WPB*32*TSTRIDE*4 = 18432 B (aliased: scan chunk needs only
// CHUNK*3*4 = 12288 B) + sIdx 512 B + sDone 16 B -> ~19 KB -> 8 blocks/CU.

__global__ __launch_bounds__(256) void qgd_kernel(
    const float* __restrict__ xyz,        // (B*N_per, 3)
    const float* __restrict__ new_xyz,    // (B*M_per, 3)
    const float* __restrict__ new_xyz_r,  // (B*M_per, 1)
    const float* __restrict__ features,   // (B*N_per, C)
    const float* __restrict__ tdec,       // (1,)
    float* __restrict__ out,
    int N_per, int M_per, int C, int M_tot, int bpb /* blocks per batch */)
{
    // numpy reference does NOT fuse mul+add; a contracted fma can flip the
    // borderline d2 < r^2 compare and change selected indices. Plain IEEE f32.
#pragma clang fp contract(off)

    __shared__ __align__(16) float sBuf[WPB * 32 * TSTRIDE];
    __shared__ int sIdx[WPB][NS];
    __shared__ int sDone[WPB];

    const int tid  = threadIdx.x;
    const int lane = tid & 63;
    const int wv   = tid >> 6;

    // block -> (batch, local query) mapping keeps all WPB queries of a block in
    // ONE batch so the cooperative xyz chunk is shared.
    const int bb    = blockIdx.x / bpb;
    const int local = (blockIdx.x % bpb) * WPB + wv;
    const bool active = (local < M_per);
    const int m     = bb * M_per + local;

    const float* xbb = xyz + (size_t)bb * N_per * 3;

    float qx=0.f, qy=0.f, qz=0.f, r_orig=0.f, real_t=0.1f, er2=-1.f;
    if (active) {
        qx = new_xyz[(size_t)m * 3 + 0];
        qy = new_xyz[(size_t)m * 3 + 1];
        qz = new_xyz[(size_t)m * 3 + 2];
        r_orig = new_xyz_r[m];
        real_t = 0.1f * tdec[0];                 // TEMPERATURE * decay
        float er = r_orig + real_t * 5.0f;       // explore radius
        er2 = er * er;
    }

    int  cnt  = 0;
    bool done = !active;
    if (lane == 0) sDone[wv] = done ? 1 : 0;
    const unsigned long long lt = (1ull << lane) - 1ull;

    // cooperative chunk loader: 3 float4 per thread, zero-fill OOB
    float4 R[3];
    auto load_chunk = [&](int base) {
        const float* src = xbb + (size_t)base * 3;
        const int avail3 = (base < N_per) ? (min(N_per - base, CHUNK) * 3) : 0;
        #pragma unroll
        for (int i = 0; i < 3; ++i) {
            const int e = 4 * (tid + 256 * i);
            float4 v = make_float4(0.f, 0.f, 0.f, 0.f);
            if (e + 3 < avail3) {
                v = *(const float4*)(src + e);
            } else if (e < avail3) {
                float t0 = src[e];
                float t1 = (e + 1 < avail3) ? src[e + 1] : 0.f;
                float t2 = (e + 2 < avail3) ? src[e + 2] : 0.f;
                v = make_float4(t0, t1, t2, 0.f);
            }
            R[i] = v;
        }
    };

    load_chunk(0);   // prefetch chunk 0

    // ---- cooperative ball-query scan ----
    for (int base = 0; base < N_per; base += CHUNK) {
        __syncthreads();          // prev scan done (sBuf free), sDone visible
        if (base > 0) {
            bool all = true;
            #pragma unroll
            for (int w = 0; w < WPB; ++w) all = all && (sDone[w] != 0);
            if (all) break;       // block-uniform
        }
        // commit prefetched chunk 'base' to LDS
        #pragma unroll
        for (int i = 0; i < 3; ++i)
            *(float4*)&sBuf[4 * (tid + 256 * i)] = R[i];
        // prefetch next chunk (latency hides behind this chunk's scan)
        load_chunk(base + CHUNK);
        __syncthreads();          // sBuf ready

        if (!done) {
            const int limit = min(N_per - base, CHUNK);
            for (int s = 0; s < CHUNK; s += 64) {
                const int pl = s + lane;
                float px = sBuf[pl * 3 + 0];
                float py = sBuf[pl * 3 + 1];
                float pz = sBuf[pl * 3 + 2];
                float dx = px - qx, dy = py - qy, dz = pz - qz;
                float d2 = dx * dx;
                d2 = d2 + dy * dy;               // numpy left-fold order
                d2 = d2 + dz * dz;
                bool hit = (pl < limit) && (d2 < er2);    // strict <
                unsigned long long msk = __ballot(hit);
                if (hit) {
                    int slot = cnt + (int)__popcll(msk & lt);
                    if (slot < NS) sIdx[wv][slot] = base + pl;
                }
                cnt += (int)__popcll(msk);       // wave-uniform
                if (cnt >= NS) break;            // wave-uniform
            }
            if (cnt >= NS) done = true;
            if (lane == 0) sDone[wv] = done ? 1 : 0;
        }
    }
    __syncthreads();              // all scans complete before LDS reuse

    const bool empty = (cnt == 0);
    // pad slots >= cnt with first hit (or 0 if empty) — matches reference
    if (active && lane < NS && lane >= cnt) {
        sIdx[wv][lane] = empty ? 0 : sIdx[wv][0];
    }
    __syncthreads();

    const int    j       = lane & 31;            // sample slot
    const size_t nf_base = (size_t)m * (3 + C) * NS;
    float* wout = out + (size_t)M_tot * (3 + C) * NS;   // weights block
    float* iout = wout + (size_t)M_tot * NS;            // idx block

    if (active && lane < NS) {
        const int pj = sIdx[wv][j];
        float gx = 0.f, gy = 0.f, gz = 0.f;
        if (!empty) {
            gx = xbb[(size_t)pj * 3 + 0] - qx;
            gy = xbb[(size_t)pj * 3 + 1] - qy;
            gz = xbb[(size_t)pj * 3 + 2] - qz;
        }
        float d2 = gx * gx;
        d2 = d2 + gy * gy;
        d2 = d2 + gz * gz;
        float dist = sqrtf(d2);
        // 1 - sigmoid(z) == 1/(1+exp(z)), z = (dist - r)/real_t
        float wt = 1.0f / (1.0f + expf((dist - r_orig) / real_t));
        out[nf_base + 0 * NS + j] = gx;
        out[nf_base + 1 * NS + j] = gy;
        out[nf_base + 2 * NS + j] = gz;
        wout[(size_t)m * NS + j] = wt;
        iout[(size_t)m * NS + j] = (float)pj;    // out buffer is f32; idx exact
    }

    // ---- grouped features: row-cooperative gather + LDS transpose ----
    // gather: 8 lanes/row -> each dwordx4 reads 8 FULL cache lines (vs ~40
    // partial). store: dwordx4 along sample dim -> 8 store instrs per pass.
    float* sT = sBuf + wv * (32 * TSTRIDE);
    const float* fb = features + (size_t)bb * N_per * C;

    int c0 = 0;
    for (; c0 + 32 <= C; c0 += 32) {
        if (active) {
            const int k = lane & 7;              // col group (4 channels)
            #pragma unroll
            for (int t = 0; t < 4; ++t) {
                const int r  = 8 * t + (lane >> 3);   // sample slot
                const int pj = sIdx[wv][r];
                float4 v = make_float4(0.f, 0.f, 0.f, 0.f);
                if (!empty) v = *(const float4*)(fb + (size_t)pj * C + c0 + 4 * k);
                sT[(4 * k + 0) * TSTRIDE + r] = v.x;
                sT[(4 * k + 1) * TSTRIDE + r] = v.y;
                sT[(4 * k + 2) * TSTRIDE + r] = v.z;
                sT[(4 * k + 3) * TSTRIDE + r] = v.w;
            }
        }
        __syncthreads();
        if (active) {
            const int jg = lane & 7;             // group of 4 samples
            #pragma unroll
            for (int s2 = 0; s2 < 4; ++s2) {
                const int ch = 8 * s2 + (lane >> 3);  // channel within pass
                float4 w = *(const float4*)&sT[ch * TSTRIDE + 4 * jg];
                *(float4*)&out[nf_base + (size_t)(3 + c0 + ch) * NS + 4 * jg] = w;
            }
        }
        __syncthreads();
    }
    // generic tail for C % 32 != 0 (dead for C=64): old per-lane dword path
    if (active && c0 < C) {
        const int h  = lane >> 5;
        const int pj = sIdx[wv][j];
        const float* frow = fb + (size_t)pj * C;
        for (int c = c0 + h; c < C; c += 2) {
            float v = empty ? 0.f : frow[c];
            out[nf_base + (size_t)(3 + c) * NS + j] = v;
        }
    }
}

extern "C" void kernel_launch(void* const* d_in, const int* in_sizes, int n_in,
                              void* d_out, int out_size, void* d_ws, size_t ws_size,
                              hipStream_t stream) {
    const float* xyz       = (const float*)d_in[0];
    // d_in[1] = xyz_batch_cnt (int32) — reference only uses its length (B)
    const float* new_xyz   = (const float*)d_in[2];
    const float* new_xyz_r = (const float*)d_in[3];
    // d_in[4] = new_xyz_batch_cnt — unused (even split, like the reference)
    const float* features  = (const float*)d_in[5];
    const float* tdec      = (const float*)d_in[6];

    const int B     = in_sizes[1];
    const int N_tot = in_sizes[0] / 3;
    const int M_tot = in_sizes[2] / 3;
    const int C     = in_sizes[5] / N_tot;
    const int N_per = N_tot / B;
    const int M_per = M_tot / B;

    const int bpb    = (M_per + WPB - 1) / WPB;   // blocks per batch
    const int blocks = B * bpb;
    qgd_kernel<<<blocks, 256, 0, stream>>>(xyz, new_xyz, new_xyz_r, features,
                                           tdec, (float*)d_out,
                                           N_per, M_per, C, M_tot, bpb);
}

// Round 4
// 127.405 us; speedup vs baseline: 1.6935x; 1.0356x over previous
//
#include <hip/hip_runtime.h>
#include <math.h>

#define NS 32          // NSAMPLE
#define WPB 4          // waves per block
#define CHUNK 1024     // points per cooperative scan chunk (12 KB LDS)
#define TSTRIDE 36     // transpose j-stride in dwords (mult of 4 -> b128-aligned)

// LDS: sBuf = WPB*32*TSTRIDE*4 = 18432 B (scan phase uses first 12288 B)
//      + sIdx 512 B + sDone 16 B  ->  ~19 KB -> 8 blocks/CU.
// Transpose bank conflicts are killed by an XOR swizzle on the sample index
// (r ^ 4*((ch>>2)&3)): write banks = 16*k0 + 8*(t^k1) + (h^4*k0) -> exact
// 2-way (free, m136); reads stay 16B-aligned (swizzle is a multiple of 4).

__global__ __launch_bounds__(256) void qgd_kernel(
    const float* __restrict__ xyz,        // (B*N_per, 3)
    const float* __restrict__ new_xyz,    // (B*M_per, 3)
    const float* __restrict__ new_xyz_r,  // (B*M_per, 1)
    const float* __restrict__ features,   // (B*N_per, C)
    const float* __restrict__ tdec,       // (1,)
    float* __restrict__ out,
    int N_per, int M_per, int C, int M_tot, int bpb /* blocks per batch */)
{
    // numpy reference does NOT fuse mul+add; a contracted fma can flip the
    // borderline d2 < r^2 compare and change selected indices. Plain IEEE f32.
#pragma clang fp contract(off)

    __shared__ __align__(16) float sBuf[WPB * 32 * TSTRIDE];
    __shared__ int sIdx[WPB][NS];
    __shared__ int sDone[WPB];

    const int tid  = threadIdx.x;
    const int lane = tid & 63;
    const int wv   = tid >> 6;

    // keep all WPB queries of a block in ONE batch so the scan chunk is shared
    const int bb    = blockIdx.x / bpb;
    const int local = (blockIdx.x % bpb) * WPB + wv;
    const bool active = (local < M_per);
    const int m     = bb * M_per + local;

    const float* xbb = xyz + (size_t)bb * N_per * 3;

    float qx=0.f, qy=0.f, qz=0.f, r_orig=0.f, real_t=0.1f, er2=-1.f;
    if (active) {
        qx = new_xyz[(size_t)m * 3 + 0];
        qy = new_xyz[(size_t)m * 3 + 1];
        qz = new_xyz[(size_t)m * 3 + 2];
        r_orig = new_xyz_r[m];
        real_t = 0.1f * tdec[0];                 // TEMPERATURE * decay
        float er = r_orig + real_t * 5.0f;       // explore radius
        er2 = er * er;
    }

    int  cnt  = 0;
    bool done = !active;
    if (lane == 0) sDone[wv] = done ? 1 : 0;     // ordered by first barrier
    const unsigned long long lt = (1ull << lane) - 1ull;

    // cooperative chunk loader: 3 float4 per thread, zero-fill OOB
    float4 R[3];
    auto load_chunk = [&](int base) {
        const float* src = xbb + (size_t)base * 3;
        const int avail3 = (base < N_per) ? (min(N_per - base, CHUNK) * 3) : 0;
        #pragma unroll
        for (int i = 0; i < 3; ++i) {
            const int e = 4 * (tid + 256 * i);
            float4 v = make_float4(0.f, 0.f, 0.f, 0.f);
            if (e + 3 < avail3) {
                v = *(const float4*)(src + e);
            } else if (e < avail3) {
                float t0 = src[e];
                float t1 = (e + 1 < avail3) ? src[e + 1] : 0.f;
                float t2 = (e + 2 < avail3) ? src[e + 2] : 0.f;
                v = make_float4(t0, t1, t2, 0.f);
            }
            R[i] = v;
        }
    };

    load_chunk(0);   // prefetch chunk 0

    // ---- cooperative ball-query scan ----
    // NO data-dependent break inside a chunk: the 16 sub-iterations are
    // independent (only the scalar cnt chain is carried), so all ds_reads
    // pipeline. Early exit is wave-granular per CHUNK via sDone.
    const int nch = (N_per + CHUNK - 1) / CHUNK;
    for (int ci = 0; ci < nch; ++ci) {
        const int base = ci * CHUNK;
        // commit prefetched chunk to LDS
        #pragma unroll
        for (int i = 0; i < 3; ++i)
            *(float4*)&sBuf[4 * (tid + 256 * i)] = R[i];
        // prefetch next chunk (hides behind this chunk's scan)
        load_chunk(base + CHUNK);
        __syncthreads();          // sBuf ready (also orders sDone writes)

        if (!done) {
            const int limit = min(N_per - base, CHUNK);
            #pragma unroll 4
            for (int s = 0; s < CHUNK; s += 64) {
                const int pl = s + lane;
                float px = sBuf[pl * 3 + 0];
                float py = sBuf[pl * 3 + 1];
                float pz = sBuf[pl * 3 + 2];
                float dx = px - qx, dy = py - qy, dz = pz - qz;
                float d2 = dx * dx;
                d2 = d2 + dy * dy;               // numpy left-fold order
                d2 = d2 + dz * dz;
                bool hit = (pl < limit) && (d2 < er2);    // strict <
                unsigned long long msk = __ballot(hit);
                if (hit) {
                    int slot = cnt + (int)__popcll(msk & lt);
                    if (slot < NS) sIdx[wv][slot] = base + pl;
                }
                cnt += (int)__popcll(msk);       // wave-uniform
            }
            if (cnt >= NS) done = true;
            if (lane == 0) sDone[wv] = done ? 1 : 0;
        }
        __syncthreads();          // scan done (sBuf reusable), sDone visible

        bool all = true;
        #pragma unroll
        for (int w = 0; w < WPB; ++w) all = all && (sDone[w] != 0);
        if (all) break;           // block-uniform
    }

    const bool empty = (cnt == 0);
    // pad slots >= cnt with first hit (or 0 if empty) — matches reference
    if (active && lane < NS && lane >= cnt) {
        sIdx[wv][lane] = empty ? 0 : sIdx[wv][0];
    }
    __syncthreads();

    const int    j       = lane & 31;            // sample slot
    const size_t nf_base = (size_t)m * (3 + C) * NS;
    float* wout = out + (size_t)M_tot * (3 + C) * NS;   // weights block
    float* iout = wout + (size_t)M_tot * NS;            // idx block

    if (active && lane < NS) {
        const int pj = sIdx[wv][j];
        float gx = 0.f, gy = 0.f, gz = 0.f;
        if (!empty) {
            gx = xbb[(size_t)pj * 3 + 0] - qx;
            gy = xbb[(size_t)pj * 3 + 1] - qy;
            gz = xbb[(size_t)pj * 3 + 2] - qz;
        }
        float d2 = gx * gx;
        d2 = d2 + gy * gy;
        d2 = d2 + gz * gz;
        float dist = sqrtf(d2);
        // 1 - sigmoid(z) == 1/(1+exp(z)), z = (dist - r)/real_t
        float wt = 1.0f / (1.0f + expf((dist - r_orig) / real_t));
        out[nf_base + 0 * NS + j] = gx;
        out[nf_base + 1 * NS + j] = gy;
        out[nf_base + 2 * NS + j] = gz;
        wout[(size_t)m * NS + j] = wt;
        iout[(size_t)m * NS + j] = (float)pj;    // out buffer is f32; idx exact
    }

    // ---- grouped features: row-cooperative gather + swizzled LDS transpose ----
    float* sT = sBuf + wv * (32 * TSTRIDE);
    const float* fb = features + (size_t)bb * N_per * C;

    int c0 = 0;
    for (; c0 + 32 <= C; c0 += 32) {
        if (active) {
            const int k  = lane & 7;             // col group (4 channels)
            const int f4 = 4 * (k & 3);          // XOR swizzle for this ch group
            #pragma unroll
            for (int t = 0; t < 4; ++t) {
                const int r  = 8 * t + (lane >> 3);   // sample slot
                const int pj = sIdx[wv][r];
                float4 v = make_float4(0.f, 0.f, 0.f, 0.f);
                if (!empty) v = *(const float4*)(fb + (size_t)pj * C + c0 + 4 * k);
                const int rs = r ^ f4;
                sT[(4 * k + 0) * TSTRIDE + rs] = v.x;
                sT[(4 * k + 1) * TSTRIDE + rs] = v.y;
                sT[(4 * k + 2) * TSTRIDE + rs] = v.z;
                sT[(4 * k + 3) * TSTRIDE + rs] = v.w;
            }
        }
        __syncthreads();
        if (active) {
            const int jg = lane & 7;             // group of 4 samples
            #pragma unroll
            for (int s2 = 0; s2 < 4; ++s2) {
                const int ch = 8 * s2 + (lane >> 3);  // channel within pass
                const int jb = (4 * jg) ^ (4 * ((ch >> 2) & 3));
                float4 w = *(const float4*)&sT[ch * TSTRIDE + jb];
                // (base+i)^4f == 4*jg + i: w = samples 4jg..4jg+3 of ch
                *(float4*)&out[nf_base + (size_t)(3 + c0 + ch) * NS + 4 * jg] = w;
            }
        }
        __syncthreads();
    }
    // generic tail for C % 32 != 0 (dead for C=64)
    if (active && c0 < C) {
        const int h  = lane >> 5;
        const int pj = sIdx[wv][j];
        const float* frow = fb + (size_t)pj * C;
        for (int c = c0 + h; c < C; c += 2) {
            float v = empty ? 0.f : frow[c];
            out[nf_base + (size_t)(3 + c) * NS + j] = v;
        }
    }
}

extern "C" void kernel_launch(void* const* d_in, const int* in_sizes, int n_in,
                              void* d_out, int out_size, void* d_ws, size_t ws_size,
                              hipStream_t stream) {
    const float* xyz       = (const float*)d_in[0];
    // d_in[1] = xyz_batch_cnt (int32) — reference only uses its length (B)
    const float* new_xyz   = (const float*)d_in[2];
    const float* new_xyz_r = (const float*)d_in[3];
    // d_in[4] = new_xyz_batch_cnt — unused (even split, like the reference)
    const float* features  = (const float*)d_in[5];
    const float* tdec      = (const float*)d_in[6];

    const int B     = in_sizes[1];
    const int N_tot = in_sizes[0] / 3;
    const int M_tot = in_sizes[2] / 3;
    const int C     = in_sizes[5] / N_tot;
    const int N_per = N_tot / B;
    const int M_per = M_tot / B;

    const int bpb    = (M_per + WPB - 1) / WPB;   // blocks per batch
    const int blocks = B * bpb;
    qgd_kernel<<<blocks, 256, 0, stream>>>(xyz, new_xyz, new_xyz_r, features,
                                           tdec, (float*)d_out,
                                           N_per, M_per, C, M_tot, bpb);
}

// Round 5
// 124.180 us; speedup vs baseline: 1.7375x; 1.0260x over previous
//
#include <hip/hip_runtime.h>
#include <math.h>

#define NS 32          // NSAMPLE
#define WPB 4          // waves per block
#define SCAN0 2048     // prefix length scanned by kernel A
#define TSTRIDE 36     // transpose j-stride in dwords (mult of 4 -> b128-aligned)

// ---------------------------------------------------------------------------
// Kernel A: per-wave prefix ball-query (first SCAN0 points). Queries that
// reach NS hits are finalized (idx written as raw int32 into the idx output
// region). Queries with cnt<NS are appended to the straggler list for B.
// No LDS, no inter-wave coupling: dense queries (~97%) exit in 1-2 batches.
// ---------------------------------------------------------------------------
__global__ __launch_bounds__(256) void qgd_scanA(
    const float* __restrict__ xyz, const float* __restrict__ new_xyz,
    const float* __restrict__ new_xyz_r, const float* __restrict__ tdec,
    int* __restrict__ idx_out,          // (M_tot, NS) int32 (aliases output)
    int* __restrict__ counter, int* __restrict__ list,
    int N_per, int M_per, int M_tot)
{
#pragma clang fp contract(off)          // keep d2 < r^2 bit-exact vs numpy
    const int lane = threadIdx.x & 63;
    const int wv   = threadIdx.x >> 6;
    const int m    = blockIdx.x * WPB + wv;
    if (m >= M_tot) return;             // wave-uniform

    const int bb = m / M_per;
    const float* xb = xyz + (size_t)bb * N_per * 3;
    const float qx = new_xyz[(size_t)m * 3 + 0];
    const float qy = new_xyz[(size_t)m * 3 + 1];
    const float qz = new_xyz[(size_t)m * 3 + 2];
    const float r_orig = new_xyz_r[m];
    const float real_t = 0.1f * tdec[0];
    const float er  = r_orig + real_t * 5.0f;
    const float er2 = er * er;
    const unsigned long long lt = (1ull << lane) - 1ull;

    const int scan0 = (SCAN0 < N_per) ? SCAN0 : N_per;
    int cnt = 0;
    for (int base = 0; base < scan0; base += 256) {
        float d2k[4];
        #pragma unroll
        for (int k = 0; k < 4; ++k) {
            int p = base + k * 64 + lane;
            int pc = (p < N_per) ? p : (N_per - 1);
            const float* pp = xb + (size_t)pc * 3;
            float dx = pp[0] - qx, dy = pp[1] - qy, dz = pp[2] - qz;
            float d2 = dx * dx;
            d2 = d2 + dy * dy;          // numpy left-fold order
            d2 = d2 + dz * dz;
            d2k[k] = (p < N_per) ? d2 : 1e30f;
        }
        #pragma unroll
        for (int k = 0; k < 4; ++k) {
            bool hit = d2k[k] < er2;    // strict <
            unsigned long long msk = __ballot(hit);
            if (hit) {
                int slot = cnt + (int)__popcll(msk & lt);
                if (slot < NS) idx_out[(size_t)m * NS + slot] = base + k * 64 + lane;
            }
            cnt += (int)__popcll(msk);  // wave-uniform
        }
        if (cnt >= NS) break;           // wave-uniform
    }
    if (cnt < NS && lane == 0) {
        int pos = atomicAdd(counter, 1);
        list[pos] = m;
    }
}

// ---------------------------------------------------------------------------
// Kernel B: full rescan for stragglers. One block per straggler query; the 4
// waves scan disjoint quarter-ranges in parallel (4x shorter critical path),
// then merge in index order in LDS. Writes ALL NS slots (padded per the
// reference; empty -> slot0 = -1 as a flag for C).
// ---------------------------------------------------------------------------
__global__ __launch_bounds__(256) void qgd_scanB(
    const float* __restrict__ xyz, const float* __restrict__ new_xyz,
    const float* __restrict__ new_xyz_r, const float* __restrict__ tdec,
    int* __restrict__ idx_out,
    const int* __restrict__ counter, const int* __restrict__ list,
    int N_per, int M_per)
{
#pragma clang fp contract(off)
    __shared__ int sH[WPB][NS];
    __shared__ int sC[WPB];

    const int lane = threadIdx.x & 63;
    const int wv   = threadIdx.x >> 6;
    const int nstrag = *counter;
    const unsigned long long lt = (1ull << lane) - 1ull;

    for (int it = blockIdx.x; it < nstrag; it += gridDim.x) {
        const int m  = list[it];
        const int bb = m / M_per;
        const float* xb = xyz + (size_t)bb * N_per * 3;
        const float qx = new_xyz[(size_t)m * 3 + 0];
        const float qy = new_xyz[(size_t)m * 3 + 1];
        const float qz = new_xyz[(size_t)m * 3 + 2];
        const float r_orig = new_xyz_r[m];
        const float real_t = 0.1f * tdec[0];
        const float er  = r_orig + real_t * 5.0f;
        const float er2 = er * er;

        const int rb = (int)(((long long)N_per * wv) / WPB);
        const int re = (int)(((long long)N_per * (wv + 1)) / WPB);

        int cnt = 0;
        for (int base = rb; base < re; base += 256) {
            float d2k[4];
            #pragma unroll
            for (int k = 0; k < 4; ++k) {
                int p = base + k * 64 + lane;
                int pc = (p < re) ? p : (re - 1);
                const float* pp = xb + (size_t)pc * 3;
                float dx = pp[0] - qx, dy = pp[1] - qy, dz = pp[2] - qz;
                float d2 = dx * dx;
                d2 = d2 + dy * dy;
                d2 = d2 + dz * dz;
                d2k[k] = (p < re) ? d2 : 1e30f;
            }
            #pragma unroll
            for (int k = 0; k < 4; ++k) {
                bool hit = d2k[k] < er2;
                unsigned long long msk = __ballot(hit);
                if (hit) {
                    int slot = cnt + (int)__popcll(msk & lt);
                    if (slot < NS) sH[wv][slot] = base + k * 64 + lane;
                }
                cnt += (int)__popcll(msk);
            }
            if (cnt >= NS) break;
        }
        if (lane == 0) sC[wv] = (cnt < NS) ? cnt : NS;
        __syncthreads();

        if (threadIdx.x < NS) {
            const int j  = threadIdx.x;
            const int c0 = sC[0], c1 = sC[1], c2 = sC[2], c3 = sC[3];
            const int o1 = c0, o2 = c0 + c1, o3 = o2 + c2;
            const int tot = o3 + c3;
            int v = 0;
            if (j < tot) {
                if      (j >= o3) v = sH[3][j - o3];
                else if (j >= o2) v = sH[2][j - o2];
                else if (j >= o1) v = sH[1][j - o1];
                else              v = sH[0][j];
            }
            int first = -1;
            if      (c0 > 0) first = sH[0][0];
            else if (c1 > 0) first = sH[1][0];
            else if (c2 > 0) first = sH[2][0];
            else if (c3 > 0) first = sH[3][0];
            int outv;
            if (tot == 0)      outv = (j == 0) ? -1 : 0;   // empty flag
            else if (j < tot)  outv = v;
            else               outv = first;               // pad with first hit
            idx_out[(size_t)m * NS + j] = outv;
        }
        __syncthreads();    // sH/sC reusable
    }
}

// ---------------------------------------------------------------------------
// Kernel C: uniform gather + write. Reads finalized idx (int) from the idx
// output region, stages to LDS, writes grouped_xyz/weights/idx(float), then
// row-cooperative feature gather + swizzled LDS transpose + float4 stores.
// ---------------------------------------------------------------------------
__global__ __launch_bounds__(256) void qgd_writeC(
    const float* __restrict__ xyz, const float* __restrict__ new_xyz,
    const float* __restrict__ new_xyz_r, const float* __restrict__ features,
    const float* __restrict__ tdec, float* __restrict__ out,
    int N_per, int M_per, int C, int M_tot)
{
#pragma clang fp contract(off)
    __shared__ __align__(16) float sBuf[WPB * 32 * TSTRIDE];
    __shared__ int sIdx[WPB][NS];

    const int lane = threadIdx.x & 63;
    const int wv   = threadIdx.x >> 6;
    const int m    = blockIdx.x * WPB + wv;
    const bool active = (m < M_tot);

    float* wout = out + (size_t)M_tot * (3 + C) * NS;
    float* iout = wout + (size_t)M_tot * NS;
    int*   iint = (int*)iout;

    if (active && lane < NS) sIdx[wv][lane] = iint[(size_t)m * NS + lane];
    __syncthreads();

    if (!active) return;

    const bool empty = (sIdx[wv][0] < 0);
    const int  bb    = m / M_per;
    const float* xb  = xyz + (size_t)bb * N_per * 3;
    const int    j   = lane & 31;
    const size_t nf_base = (size_t)m * (3 + C) * NS;

    if (lane < NS) {
        const float qx = new_xyz[(size_t)m * 3 + 0];
        const float qy = new_xyz[(size_t)m * 3 + 1];
        const float qz = new_xyz[(size_t)m * 3 + 2];
        const float r_orig = new_xyz_r[m];
        const float real_t = 0.1f * tdec[0];
        const int pj = empty ? 0 : sIdx[wv][j];
        float gx = 0.f, gy = 0.f, gz = 0.f;
        if (!empty) {
            gx = xb[(size_t)pj * 3 + 0] - qx;
            gy = xb[(size_t)pj * 3 + 1] - qy;
            gz = xb[(size_t)pj * 3 + 2] - qz;
        }
        float d2 = gx * gx;
        d2 = d2 + gy * gy;
        d2 = d2 + gz * gz;
        float dist = sqrtf(d2);
        float wt = 1.0f / (1.0f + expf((dist - r_orig) / real_t)); // 1-sigmoid
        out[nf_base + 0 * NS + j] = gx;
        out[nf_base + 1 * NS + j] = gy;
        out[nf_base + 2 * NS + j] = gz;
        wout[(size_t)m * NS + j] = wt;
        iout[(size_t)m * NS + j] = (float)pj;   // overwrites int idx in place
    }

    // features: row-cooperative gather + XOR-swizzled LDS transpose
    float* sT = sBuf + wv * (32 * TSTRIDE);
    const float* fb = features + (size_t)bb * N_per * C;

    int c0 = 0;
    for (; c0 + 32 <= C; c0 += 32) {
        {
            const int k  = lane & 7;
            const int f4 = 4 * (k & 3);
            #pragma unroll
            for (int t = 0; t < 4; ++t) {
                const int r  = 8 * t + (lane >> 3);
                const int pj = empty ? 0 : sIdx[wv][r];
                float4 v = make_float4(0.f, 0.f, 0.f, 0.f);
                if (!empty) v = *(const float4*)(fb + (size_t)pj * C + c0 + 4 * k);
                const int rs = r ^ f4;
                sT[(4 * k + 0) * TSTRIDE + rs] = v.x;
                sT[(4 * k + 1) * TSTRIDE + rs] = v.y;
                sT[(4 * k + 2) * TSTRIDE + rs] = v.z;
                sT[(4 * k + 3) * TSTRIDE + rs] = v.w;
            }
        }
        __syncthreads();
        {
            const int jg = lane & 7;
            #pragma unroll
            for (int s2 = 0; s2 < 4; ++s2) {
                const int ch = 8 * s2 + (lane >> 3);
                const int jb = (4 * jg) ^ (4 * ((ch >> 2) & 3));
                float4 w = *(const float4*)&sT[ch * TSTRIDE + jb];
                *(float4*)&out[nf_base + (size_t)(3 + c0 + ch) * NS + 4 * jg] = w;
            }
        }
        __syncthreads();
    }
    if (c0 < C) {   // tail for C % 32 != 0 (dead for C=64)
        const int h  = lane >> 5;
        const int pj = empty ? 0 : sIdx[wv][j];
        const float* frow = fb + (size_t)pj * C;
        for (int c = c0 + h; c < C; c += 2) {
            float v = empty ? 0.f : frow[c];
            out[nf_base + (size_t)(3 + c) * NS + j] = v;
        }
    }
}

extern "C" void kernel_launch(void* const* d_in, const int* in_sizes, int n_in,
                              void* d_out, int out_size, void* d_ws, size_t ws_size,
                              hipStream_t stream) {
    const float* xyz       = (const float*)d_in[0];
    const float* new_xyz   = (const float*)d_in[2];
    const float* new_xyz_r = (const float*)d_in[3];
    const float* features  = (const float*)d_in[5];
    const float* tdec      = (const float*)d_in[6];

    const int B     = in_sizes[1];
    const int N_tot = in_sizes[0] / 3;
    const int M_tot = in_sizes[2] / 3;
    const int C     = in_sizes[5] / N_tot;
    const int N_per = N_tot / B;
    const int M_per = M_tot / B;

    float* out  = (float*)d_out;
    int*   iint = (int*)(out + (size_t)M_tot * (3 + C) * NS + (size_t)M_tot * NS);
    int*   counter = (int*)d_ws;
    int*   list    = (int*)d_ws + 4;    // 16B offset; needs (M_tot+4)*4 bytes

    hipMemsetAsync(counter, 0, sizeof(int), stream);

    const int blocksA = (M_tot + WPB - 1) / WPB;
    qgd_scanA<<<blocksA, 256, 0, stream>>>(xyz, new_xyz, new_xyz_r, tdec,
                                           iint, counter, list,
                                           N_per, M_per, M_tot);
    qgd_scanB<<<512, 256, 0, stream>>>(xyz, new_xyz, new_xyz_r, tdec,
                                       iint, counter, list, N_per, M_per);
    const int blocksC = (M_tot + WPB - 1) / WPB;
    qgd_writeC<<<blocksC, 256, 0, stream>>>(xyz, new_xyz, new_xyz_r, features,
                                            tdec, out, N_per, M_per, C, M_tot);
}

// Round 6
// 119.212 us; speedup vs baseline: 1.8099x; 1.0417x over previous
//
#include <hip/hip_runtime.h>
#include <math.h>

#define NS 32          // NSAMPLE
#define WPB 4          // waves per block
#define SCAN0 2048     // prefix length scanned by kernel AC
#define TSTRIDE 36     // transpose j-stride in dwords (mult of 4 -> b128-aligned)

// ---------------------------------------------------------------------------
// Per-WAVE output epilogue for one query m. Uses only this wave's LDS tile
// (sT, 32*TSTRIDE floats) and idx list (sIdxW, 32 ints). All LDS use is
// wave-internal: 64 lanes execute in lockstep and the compiler inserts
// lgkmcnt waits for the write->read dependency, so NO __syncthreads needed.
// XOR swizzle (r ^ 4*(k&3)) makes transpose writes exactly 2-way banked
// (free, m136) while keeping reads 16B-aligned.
// ---------------------------------------------------------------------------
__device__ __forceinline__ void write_query(
    int m, int bb, bool empty, int lane,
    const int* sIdxW, float* sT,
    const float* __restrict__ xyz, const float* __restrict__ new_xyz,
    const float* __restrict__ new_xyz_r, const float* __restrict__ features,
    float real_t, float* __restrict__ out, int N_per, int C, int M_tot)
{
#pragma clang fp contract(off)
    const float* xb = xyz + (size_t)bb * N_per * 3;
    const int    j  = lane & 31;
    const size_t nf_base = (size_t)m * (3 + C) * NS;
    float* wout = out + (size_t)M_tot * (3 + C) * NS;
    float* iout = wout + (size_t)M_tot * NS;

    if (lane < NS) {
        const float qx = new_xyz[(size_t)m * 3 + 0];
        const float qy = new_xyz[(size_t)m * 3 + 1];
        const float qz = new_xyz[(size_t)m * 3 + 2];
        const float r_orig = new_xyz_r[m];
        const int pj = empty ? 0 : sIdxW[j];
        float gx = 0.f, gy = 0.f, gz = 0.f;
        if (!empty) {
            gx = xb[(size_t)pj * 3 + 0] - qx;
            gy = xb[(size_t)pj * 3 + 1] - qy;
            gz = xb[(size_t)pj * 3 + 2] - qz;
        }
        float d2 = gx * gx;
        d2 = d2 + gy * gy;
        d2 = d2 + gz * gz;
        float dist = sqrtf(d2);
        float wt = 1.0f / (1.0f + expf((dist - r_orig) / real_t)); // 1-sigmoid
        out[nf_base + 0 * NS + j] = gx;
        out[nf_base + 1 * NS + j] = gy;
        out[nf_base + 2 * NS + j] = gz;
        wout[(size_t)m * NS + j] = wt;
        iout[(size_t)m * NS + j] = (float)pj;   // f32 buffer; idx exact
    }

    const float* fb = features + (size_t)bb * N_per * C;
    int c0 = 0;
    for (; c0 + 32 <= C; c0 += 32) {
        const int k  = lane & 7;                 // col group (4 channels)
        const int f4 = 4 * (k & 3);              // XOR swizzle
        #pragma unroll
        for (int t = 0; t < 4; ++t) {
            const int r  = 8 * t + (lane >> 3);  // sample slot
            const int pj = empty ? 0 : sIdxW[r];
            float4 v = make_float4(0.f, 0.f, 0.f, 0.f);
            if (!empty) v = *(const float4*)(fb + (size_t)pj * C + c0 + 4 * k);
            const int rs = r ^ f4;
            sT[(4 * k + 0) * TSTRIDE + rs] = v.x;
            sT[(4 * k + 1) * TSTRIDE + rs] = v.y;
            sT[(4 * k + 2) * TSTRIDE + rs] = v.z;
            sT[(4 * k + 3) * TSTRIDE + rs] = v.w;
        }
        // wave-internal LDS dependency: lockstep + lgkmcnt, no barrier
        const int jg = lane & 7;                 // group of 4 samples
        #pragma unroll
        for (int s2 = 0; s2 < 4; ++s2) {
            const int ch = 8 * s2 + (lane >> 3); // channel within pass
            const int jb = (4 * jg) ^ (4 * ((ch >> 2) & 3));
            float4 w = *(const float4*)&sT[ch * TSTRIDE + jb];
            *(float4*)&out[nf_base + (size_t)(3 + c0 + ch) * NS + 4 * jg] = w;
        }
    }
    if (c0 < C) {   // tail for C % 32 != 0 (dead for C=64)
        const int h  = lane >> 5;
        const int pj = empty ? 0 : sIdxW[j];
        const float* frow = fb + (size_t)pj * C;
        for (int c = c0 + h; c < C; c += 2) {
            float v = empty ? 0.f : frow[c];
            out[nf_base + (size_t)(3 + c) * NS + j] = v;
        }
    }
}

// ---------------------------------------------------------------------------
// Kernel AC: per-wave prefix ball-query (first SCAN0 points). Queries that
// reach NS hits write ALL their outputs immediately (per-wave epilogue, no
// barriers anywhere -> waves fully decoupled). cnt<NS -> straggler list.
// ---------------------------------------------------------------------------
__global__ __launch_bounds__(256) void qgd_AC(
    const float* __restrict__ xyz, const float* __restrict__ new_xyz,
    const float* __restrict__ new_xyz_r, const float* __restrict__ features,
    const float* __restrict__ tdec, float* __restrict__ out,
    int* __restrict__ counter, int* __restrict__ list,
    int N_per, int M_per, int C, int M_tot)
{
#pragma clang fp contract(off)          // keep d2 < r^2 bit-exact vs numpy
    __shared__ __align__(16) float sBuf[WPB * 32 * TSTRIDE];
    __shared__ int sIdx[WPB][NS];

    const int lane = threadIdx.x & 63;
    const int wv   = threadIdx.x >> 6;
    const int m    = blockIdx.x * WPB + wv;
    if (m >= M_tot) return;             // wave-uniform; kernel is barrier-free

    const int bb = m / M_per;
    const float* xb = xyz + (size_t)bb * N_per * 3;
    const float qx = new_xyz[(size_t)m * 3 + 0];
    const float qy = new_xyz[(size_t)m * 3 + 1];
    const float qz = new_xyz[(size_t)m * 3 + 2];
    const float real_t = 0.1f * tdec[0];
    const float er  = new_xyz_r[m] + real_t * 5.0f;
    const float er2 = er * er;
    const unsigned long long lt = (1ull << lane) - 1ull;

    const int scan0 = (SCAN0 < N_per) ? SCAN0 : N_per;
    int cnt = 0;
    for (int base = 0; base < scan0; base += 256) {
        float d2k[4];
        #pragma unroll
        for (int k = 0; k < 4; ++k) {
            int p = base + k * 64 + lane;
            int pc = (p < N_per) ? p : (N_per - 1);
            const float* pp = xb + (size_t)pc * 3;
            float dx = pp[0] - qx, dy = pp[1] - qy, dz = pp[2] - qz;
            float d2 = dx * dx;
            d2 = d2 + dy * dy;          // numpy left-fold order
            d2 = d2 + dz * dz;
            d2k[k] = (p < N_per) ? d2 : 1e30f;
        }
        #pragma unroll
        for (int k = 0; k < 4; ++k) {
            bool hit = d2k[k] < er2;    // strict <
            unsigned long long msk = __ballot(hit);
            if (hit) {
                int slot = cnt + (int)__popcll(msk & lt);
                if (slot < NS) sIdx[wv][slot] = base + k * 64 + lane;
            }
            cnt += (int)__popcll(msk);  // wave-uniform
        }
        if (cnt >= NS) break;           // wave-uniform
    }

    if (cnt >= NS) {
        write_query(m, bb, /*empty=*/false, lane, sIdx[wv],
                    sBuf + wv * (32 * TSTRIDE),
                    xyz, new_xyz, new_xyz_r, features, real_t, out,
                    N_per, C, M_tot);
    } else if (lane == 0) {
        int pos = atomicAdd(counter, 1);
        list[pos] = m;
    }
}

// ---------------------------------------------------------------------------
// Kernel B: straggler full rescan + write. One block per straggler; 4 waves
// scan disjoint quarter-ranges, in-order LDS merge gives exact first-NS
// semantics, then wave 0 runs the epilogue for that query.
// ---------------------------------------------------------------------------
__global__ __launch_bounds__(256) void qgd_B(
    const float* __restrict__ xyz, const float* __restrict__ new_xyz,
    const float* __restrict__ new_xyz_r, const float* __restrict__ features,
    const float* __restrict__ tdec, float* __restrict__ out,
    const int* __restrict__ counter, const int* __restrict__ list,
    int N_per, int M_per, int C, int M_tot)
{
#pragma clang fp contract(off)
    __shared__ int sH[WPB][NS];
    __shared__ int sC[WPB];
    __shared__ int sM[NS];
    __shared__ int sTot;
    __shared__ __align__(16) float sT[32 * TSTRIDE];

    const int lane = threadIdx.x & 63;
    const int wv   = threadIdx.x >> 6;
    const int nstrag = *counter;
    const unsigned long long lt = (1ull << lane) - 1ull;
    const float real_t = 0.1f * tdec[0];

    for (int it = blockIdx.x; it < nstrag; it += gridDim.x) {
        const int m  = list[it];
        const int bb = m / M_per;
        const float* xb = xyz + (size_t)bb * N_per * 3;
        const float qx = new_xyz[(size_t)m * 3 + 0];
        const float qy = new_xyz[(size_t)m * 3 + 1];
        const float qz = new_xyz[(size_t)m * 3 + 2];
        const float er  = new_xyz_r[m] + real_t * 5.0f;
        const float er2 = er * er;

        const int rb = (int)(((long long)N_per * wv) / WPB);
        const int re = (int)(((long long)N_per * (wv + 1)) / WPB);

        int cnt = 0;
        for (int base = rb; base < re; base += 256) {
            float d2k[4];
            #pragma unroll
            for (int k = 0; k < 4; ++k) {
                int p = base + k * 64 + lane;
                int pc = (p < re) ? p : (re - 1);
                const float* pp = xb + (size_t)pc * 3;
                float dx = pp[0] - qx, dy = pp[1] - qy, dz = pp[2] - qz;
                float d2 = dx * dx;
                d2 = d2 + dy * dy;
                d2 = d2 + dz * dz;
                d2k[k] = (p < re) ? d2 : 1e30f;
            }
            #pragma unroll
            for (int k = 0; k < 4; ++k) {
                bool hit = d2k[k] < er2;
                unsigned long long msk = __ballot(hit);
                if (hit) {
                    int slot = cnt + (int)__popcll(msk & lt);
                    if (slot < NS) sH[wv][slot] = base + k * 64 + lane;
                }
                cnt += (int)__popcll(msk);
            }
            if (cnt >= NS) break;
        }
        if (lane == 0) sC[wv] = (cnt < NS) ? cnt : NS;
        __syncthreads();                 // sH/sC ready

        if (threadIdx.x < NS) {          // in-order merge (wave 0 lanes)
            const int j  = threadIdx.x;
            const int c0 = sC[0], c1 = sC[1], c2 = sC[2], c3 = sC[3];
            const int o1 = c0, o2 = c0 + c1, o3 = o2 + c2;
            const int tot = o3 + c3;
            int v = 0;
            if (j < tot) {
                if      (j >= o3) v = sH[3][j - o3];
                else if (j >= o2) v = sH[2][j - o2];
                else if (j >= o1) v = sH[1][j - o1];
                else              v = sH[0][j];
            }
            int first = 0;
            if      (c0 > 0) first = sH[0][0];
            else if (c1 > 0) first = sH[1][0];
            else if (c2 > 0) first = sH[2][0];
            else if (c3 > 0) first = sH[3][0];
            sM[j] = (tot == 0) ? 0 : ((j < tot) ? v : first);
            if (j == 0) sTot = tot;
        }
        __syncthreads();                 // sM/sTot ready

        if (wv == 0) {
            write_query(m, bb, /*empty=*/(sTot == 0), lane, sM, sT,
                        xyz, new_xyz, new_xyz_r, features, real_t, out,
                        N_per, C, M_tot);
        }
        __syncthreads();                 // tiles reusable next iteration
    }
}

extern "C" void kernel_launch(void* const* d_in, const int* in_sizes, int n_in,
                              void* d_out, int out_size, void* d_ws, size_t ws_size,
                              hipStream_t stream) {
    const float* xyz       = (const float*)d_in[0];
    const float* new_xyz   = (const float*)d_in[2];
    const float* new_xyz_r = (const float*)d_in[3];
    const float* features  = (const float*)d_in[5];
    const float* tdec      = (const float*)d_in[6];

    const int B     = in_sizes[1];
    const int N_tot = in_sizes[0] / 3;
    const int M_tot = in_sizes[2] / 3;
    const int C     = in_sizes[5] / N_tot;
    const int N_per = N_tot / B;
    const int M_per = M_tot / B;

    float* out     = (float*)d_out;
    int*   counter = (int*)d_ws;
    int*   list    = (int*)d_ws + 4;    // 16B offset; needs (M_tot+4)*4 bytes

    hipMemsetAsync(counter, 0, sizeof(int), stream);

    const int blocksA = (M_tot + WPB - 1) / WPB;
    qgd_AC<<<blocksA, 256, 0, stream>>>(xyz, new_xyz, new_xyz_r, features,
                                        tdec, out, counter, list,
                                        N_per, M_per, C, M_tot);
    qgd_B<<<512, 256, 0, stream>>>(xyz, new_xyz, new_xyz_r, features,
                                   tdec, out, counter, list,
                                   N_per, M_per, C, M_tot);
}